// Round 1
// baseline (412.102 us; speedup 1.0000x reference)
//
#include <hip/hip_runtime.h>

// ISTA with T=5, LAM=0.1, B=L=4096, K=128.
// y, h constant across iterations => residual/update constant =>
//   u = corr(y - corr(y,h), rev(h));  x = 5x soft_threshold(x + s*u).
// One block per row; full row + halo staged in LDS; r kept in LDS only.

#define NROWS 4096
#define LCOLS 4096
#define BLOCK 256
#define NO 16          // outputs per thread
#define YS_N 4368      // y stage: cols [-128, 4240), zeros outside [0,4096)
#define RS_N 4240      // r stage: cols [-64, 4176), real values [0,4224) idx
#define LAM 0.1f

// 128-tap correlation over `src` starting at window base q (q % 16 == 0).
// acc[k] += sum_{m=0..127} src[q + 1 + m + k] * kern[m],
// kern[m] = h[m] (REV=false) or h[127-m] (REV=true).
template <bool REV>
__device__ __forceinline__ void conv128(const float* src, int q,
                                        const float4* __restrict__ h4,
                                        float* acc) {
  const float4* b4 = reinterpret_cast<const float4*>(src + q);
  float w[20];
#pragma unroll
  for (int i = 0; i < 5; ++i) {
    float4 v = b4[i];
    w[4 * i + 0] = v.x; w[4 * i + 1] = v.y;
    w[4 * i + 2] = v.z; w[4 * i + 3] = v.w;
  }
#pragma unroll
  for (int g = 0; g < 32; ++g) {
    float4 hr = REV ? h4[31 - g] : h4[g];  // uniform -> scalar load
    float h0 = REV ? hr.w : hr.x;
    float h1 = REV ? hr.z : hr.y;
    float h2 = REV ? hr.y : hr.z;
    float h3 = REV ? hr.x : hr.w;
#pragma unroll
    for (int k = 0; k < NO; ++k) acc[k] = fmaf(w[1 + k], h0, acc[k]);
#pragma unroll
    for (int k = 0; k < NO; ++k) acc[k] = fmaf(w[2 + k], h1, acc[k]);
#pragma unroll
    for (int k = 0; k < NO; ++k) acc[k] = fmaf(w[3 + k], h2, acc[k]);
#pragma unroll
    for (int k = 0; k < NO; ++k) acc[k] = fmaf(w[4 + k], h3, acc[k]);
    if (g < 31) {
#pragma unroll
      for (int i = 0; i < 16; ++i) w[i] = w[i + 4];
      float4 nv = b4[g + 5];
      w[16] = nv.x; w[17] = nv.y; w[18] = nv.z; w[19] = nv.w;
    }
  }
}

__global__ __launch_bounds__(BLOCK) void ista_kernel(
    const float* __restrict__ y, const float* __restrict__ h,
    const float* __restrict__ step, float* __restrict__ out) {
  __shared__ __align__(16) float ys[YS_N];
  __shared__ __align__(16) float rs[RS_N];

  const int tid = threadIdx.x;
  const int row = blockIdx.x;
  const float* yrow = y + (size_t)row * LCOLS;
  const float4* h4 = reinterpret_cast<const float4*>(h);

  // Stage y row with halo; zero-fill outside [0, L) and in pad tail.
  for (int p4 = tid; p4 < YS_N / 4; p4 += BLOCK) {
    int col = p4 * 4 - 128;
    float4 v;
    if (col >= 0 && col <= LCOLS - 4) {
      v = *reinterpret_cast<const float4*>(yrow + col);
    } else {
      float a0 = (col + 0 >= 0 && col + 0 < LCOLS) ? yrow[col + 0] : 0.f;
      float a1 = (col + 1 >= 0 && col + 1 < LCOLS) ? yrow[col + 1] : 0.f;
      float a2 = (col + 2 >= 0 && col + 2 < LCOLS) ? yrow[col + 2] : 0.f;
      float a3 = (col + 3 >= 0 && col + 3 < LCOLS) ? yrow[col + 3] : 0.f;
      v = make_float4(a0, a1, a2, a3);
    }
    *reinterpret_cast<float4*>(ys + p4 * 4) = v;
  }
  __syncthreads();

  // conv1: r[col] = y[col] - corr(y,h)[col]; rs index q <-> col = q - 64.
  for (int qb = 0; qb < 4224; qb += BLOCK * NO) {
    int q = qb + tid * NO;
    if (q < 4224) {
      float acc[NO];
#pragma unroll
      for (int k = 0; k < NO; ++k) acc[k] = 0.f;
      conv128<false>(ys, q, h4, acc);
#pragma unroll
      for (int k = 0; k < NO; ++k) {
        int qk = q + k;
        float v = ys[qk + 64] - acc[k];           // y[col] - conv
        acc[k] = (qk >= 64 && qk < 4160) ? v : 0.f;  // zero-pad outside row
      }
#pragma unroll
      for (int kk = 0; kk < NO / 4; ++kk)
        *reinterpret_cast<float4*>(rs + q + kk * 4) =
            make_float4(acc[kk * 4 + 0], acc[kk * 4 + 1],
                        acc[kk * 4 + 2], acc[kk * 4 + 3]);
    }
  }
  if (tid < 4)
    *reinterpret_cast<float4*>(rs + 4224 + tid * 4) =
        make_float4(0.f, 0.f, 0.f, 0.f);
  __syncthreads();

  // conv2: u[i] = corr(r, rev(h))[i]; then 5 soft-threshold steps.
  {
    int j = tid * NO;
    float acc[NO];
#pragma unroll
    for (int k = 0; k < NO; ++k) acc[k] = 0.f;
    conv128<true>(rs, j, h4, acc);

    const float s = step[0];
    float xv[NO];
#pragma unroll
    for (int k = 0; k < NO; ++k) {
      float su = s * acc[k];
      float x = 0.f;
#pragma unroll
      for (int it = 0; it < 5; ++it) {
        x += su;
        float ax = fabsf(x) - LAM;
        ax = ax > 0.f ? ax : 0.f;
        x = copysignf(ax, x);
      }
      xv[k] = x;
    }
    float* orow = out + (size_t)row * LCOLS + j;
#pragma unroll
    for (int kk = 0; kk < NO / 4; ++kk)
      *reinterpret_cast<float4*>(orow + kk * 4) =
          make_float4(xv[kk * 4 + 0], xv[kk * 4 + 1],
                      xv[kk * 4 + 2], xv[kk * 4 + 3]);
  }
}

extern "C" void kernel_launch(void* const* d_in, const int* in_sizes, int n_in,
                              void* d_out, int out_size, void* d_ws,
                              size_t ws_size, hipStream_t stream) {
  const float* y = (const float*)d_in[0];
  const float* h = (const float*)d_in[1];
  const float* s = (const float*)d_in[2];
  float* out = (float*)d_out;
  ista_kernel<<<dim3(NROWS), dim3(BLOCK), 0, stream>>>(y, h, s, out);
}

// Round 2
// 207.431 us; speedup vs baseline: 1.9867x; 1.9867x over previous
//
#include <hip/hip_runtime.h>

// ISTA with T=5, LAM=0.1, B=L=4096, K=128.
// y, h constant across iterations => residual/update constant =>
//   u = corr(y - corr(y,h), rev(h));  x = 5x soft_threshold(x + s*u).
// One block per row; row + halo staged in LDS.
// R2: LDS pad-swizzle phys_f4(l) = l + (l>>2) — breaks the 64B-lane-stride
// 32-way bank conflict (1.71e8 conflict cycles in R1).

#define NROWS 4096
#define LCOLS 4096
#define BLOCK 256
#define NO 16          // outputs per thread
#define YS_L4 1092     // y stage: 4368 floats logical (cols [-128, 4240))
#define RS_L4 1060     // r stage: 4240 floats logical (cols [-64, 4176))
#define LAM 0.1f

__device__ __forceinline__ int sw4(int l) { return l + (l >> 2); }

// Physical sizes: sw4(YS_L4-1)+1, sw4(RS_L4-1)+1
#define YS_P4 1364
#define RS_P4 1324

// 128-tap correlation; logical float4 window base l0 (l0*4 % 16 == 0 region).
// acc[k] += sum_{m=0..127} srcf[(l0*4) + 1 + m + k] * kern[m],
// kern[m] = h[m] (REV=false) or h[127-m] (REV=true).
template <bool REV>
__device__ __forceinline__ void conv128(const float4* src4, int l0,
                                        const float4* __restrict__ h4,
                                        float* acc) {
  float w[20];
#pragma unroll
  for (int i = 0; i < 5; ++i) {
    float4 v = src4[sw4(l0 + i)];
    w[4 * i + 0] = v.x; w[4 * i + 1] = v.y;
    w[4 * i + 2] = v.z; w[4 * i + 3] = v.w;
  }
#pragma unroll
  for (int g = 0; g < 32; ++g) {
    float4 hr = REV ? h4[31 - g] : h4[g];  // uniform -> scalar load
    float h0 = REV ? hr.w : hr.x;
    float h1 = REV ? hr.z : hr.y;
    float h2 = REV ? hr.y : hr.z;
    float h3 = REV ? hr.x : hr.w;
#pragma unroll
    for (int k = 0; k < NO; ++k) acc[k] = fmaf(w[1 + k], h0, acc[k]);
#pragma unroll
    for (int k = 0; k < NO; ++k) acc[k] = fmaf(w[2 + k], h1, acc[k]);
#pragma unroll
    for (int k = 0; k < NO; ++k) acc[k] = fmaf(w[3 + k], h2, acc[k]);
#pragma unroll
    for (int k = 0; k < NO; ++k) acc[k] = fmaf(w[4 + k], h3, acc[k]);
    if (g < 31) {
#pragma unroll
      for (int i = 0; i < 16; ++i) w[i] = w[i + 4];
      float4 nv = src4[sw4(l0 + g + 5)];
      w[16] = nv.x; w[17] = nv.y; w[18] = nv.z; w[19] = nv.w;
    }
  }
}

__global__ __launch_bounds__(BLOCK) void ista_kernel(
    const float* __restrict__ y, const float* __restrict__ h,
    const float* __restrict__ step, float* __restrict__ out) {
  __shared__ __align__(16) float4 ys4[YS_P4];
  __shared__ __align__(16) float4 rs4[RS_P4];
  const float* ysf = reinterpret_cast<const float*>(ys4);

  const int tid = threadIdx.x;
  const int row = blockIdx.x;
  const float* yrow = y + (size_t)row * LCOLS;
  const float4* h4 = reinterpret_cast<const float4*>(h);

  // Stage y row with halo; zero-fill outside [0, L) and in pad tail.
  for (int p4 = tid; p4 < YS_L4; p4 += BLOCK) {
    int col = p4 * 4 - 128;
    float4 v;
    if (col >= 0 && col <= LCOLS - 4) {
      v = *reinterpret_cast<const float4*>(yrow + col);
    } else {
      float a0 = (col + 0 >= 0 && col + 0 < LCOLS) ? yrow[col + 0] : 0.f;
      float a1 = (col + 1 >= 0 && col + 1 < LCOLS) ? yrow[col + 1] : 0.f;
      float a2 = (col + 2 >= 0 && col + 2 < LCOLS) ? yrow[col + 2] : 0.f;
      float a3 = (col + 3 >= 0 && col + 3 < LCOLS) ? yrow[col + 3] : 0.f;
      v = make_float4(a0, a1, a2, a3);
    }
    ys4[sw4(p4)] = v;
  }
  __syncthreads();

  // conv1: r[col] = y[col] - corr(y,h)[col]; rs float-index q <-> col = q - 64.
  for (int qb = 0; qb < 4224; qb += BLOCK * NO) {
    int q = qb + tid * NO;
    if (q < 4224) {
      float acc[NO];
#pragma unroll
      for (int k = 0; k < NO; ++k) acc[k] = 0.f;
      conv128<false>(ys4, q >> 2, h4, acc);
#pragma unroll
      for (int k = 0; k < NO; ++k) {
        int qk = q + k;
        int e = qk + 64;                           // ys float index of y[col]
        float yv = ysf[sw4(e >> 2) * 4 + (e & 3)];
        float v = yv - acc[k];
        acc[k] = (qk >= 64 && qk < 4160) ? v : 0.f;  // zero-pad outside row
      }
#pragma unroll
      for (int kk = 0; kk < NO / 4; ++kk)
        rs4[sw4((q >> 2) + kk)] =
            make_float4(acc[kk * 4 + 0], acc[kk * 4 + 1],
                        acc[kk * 4 + 2], acc[kk * 4 + 3]);
    }
  }
  if (tid < 4) rs4[sw4(1056 + tid)] = make_float4(0.f, 0.f, 0.f, 0.f);
  __syncthreads();

  // conv2: u[i] = corr(r, rev(h))[i]; then 5 soft-threshold steps.
  {
    int j = tid * NO;
    float acc[NO];
#pragma unroll
    for (int k = 0; k < NO; ++k) acc[k] = 0.f;
    conv128<true>(rs4, tid * 4, h4, acc);

    const float s = step[0];
    float xv[NO];
#pragma unroll
    for (int k = 0; k < NO; ++k) {
      float su = s * acc[k];
      float x = 0.f;
#pragma unroll
      for (int it = 0; it < 5; ++it) {
        x += su;
        float ax = fabsf(x) - LAM;
        ax = ax > 0.f ? ax : 0.f;
        x = copysignf(ax, x);
      }
      xv[k] = x;
    }
    float* orow = out + (size_t)row * LCOLS + j;
#pragma unroll
    for (int kk = 0; kk < NO / 4; ++kk)
      *reinterpret_cast<float4*>(orow + kk * 4) =
          make_float4(xv[kk * 4 + 0], xv[kk * 4 + 1],
                      xv[kk * 4 + 2], xv[kk * 4 + 3]);
  }
}

extern "C" void kernel_launch(void* const* d_in, const int* in_sizes, int n_in,
                              void* d_out, int out_size, void* d_ws,
                              size_t ws_size, hipStream_t stream) {
  const float* y = (const float*)d_in[0];
  const float* h = (const float*)d_in[1];
  const float* s = (const float*)d_in[2];
  float* out = (float*)d_out;
  ista_kernel<<<dim3(NROWS), dim3(BLOCK), 0, stream>>>(y, h, s, out);
}

// Round 3
// 143.856 us; speedup vs baseline: 2.8647x; 1.4419x over previous
//
#include <hip/hip_runtime.h>

// ISTA T=5, LAM=0.1, B=L=4096, K=128. Loop-invariant algebra:
//   u = corr(y - corr(y,h), rev(h));  x = 5x soft_thresh(x + s*u).
// R3: MFMA formulation. Both convs are banded-Toeplitz GEMMs:
//   D[i][b] = sum_j T[i][j] * y[b][j], tiled 16(i) x 16(b) x 32(j).
// A = Toeplitz(h) fragments (wave-uniform, 5 K-chunks/conv, built once).
// B = data fragments: lane holds 8 consecutive L-elems of row (lane&15)
//     -> straight 16B LDS loads, no transpose.
// acc init = -y makes conv1 emit -r; conv2 A-frags carry -h => u = T2*r.

typedef __bf16 bf16;
typedef __bf16 bf16x4 __attribute__((ext_vector_type(4)));
typedef __bf16 bf16x8 __attribute__((ext_vector_type(8)));
typedef float f32x4 __attribute__((ext_vector_type(4)));

#define LC 512     // L-chunk per block
#define PY 824     // y-stage pitch (bf16): 1648 B = 412 dw, 412%32=28 -> 2/bank
#define PR 664     // r-stage pitch (bf16): 1328 B = 332 dw, 332%32=12 -> 2/bank
#define LAM 0.1f

__global__ __launch_bounds__(256) void ista_mfma(
    const float* __restrict__ y, const float* __restrict__ h,
    const float* __restrict__ step, float* __restrict__ out) {
  __shared__ __align__(16) bf16 ys[16 * PY];  // L-positions [-128, LC+160) + slack
  __shared__ __align__(16) bf16 rs[16 * PR];  // -r, L-positions [-64, LC+80)
  __shared__ float hs[128];

  const int tid = threadIdx.x;
  const int lane = tid & 63;
  const int wave = tid >> 6;
  const int li = lane & 15;   // A-row index i AND B/C column index b
  const int quad = lane >> 4;
  const int chunk0 = blockIdx.x * LC;
  const int b0 = blockIdx.y * 16;

  if (tid < 128) hs[tid] = h[tid];

  // ---- stage y (fp32 global -> bf16 LDS), rows of 16 threads each ----
  {
    const int rr = tid >> 4;
    const int t = tid & 15;
    const float* yrow = y + (size_t)(b0 + rr) * 4096;
    bf16* dst = ys + rr * PY;
    for (int s4 = t; s4 < 200; s4 += 16) {   // 800 bf16 per row
      int l = chunk0 - 128 + s4 * 4;
      float4 v;
      if (l >= 0 && l <= 4096 - 4) {
        v = *reinterpret_cast<const float4*>(yrow + l);
      } else {
        v.x = (l + 0 >= 0 && l + 0 < 4096) ? yrow[l + 0] : 0.f;
        v.y = (l + 1 >= 0 && l + 1 < 4096) ? yrow[l + 1] : 0.f;
        v.z = (l + 2 >= 0 && l + 2 < 4096) ? yrow[l + 2] : 0.f;
        v.w = (l + 3 >= 0 && l + 3 < 4096) ? yrow[l + 3] : 0.f;
      }
      bf16x4 bv;
      bv[0] = (bf16)v.x; bv[1] = (bf16)v.y; bv[2] = (bf16)v.z; bv[3] = (bf16)v.w;
      *reinterpret_cast<bf16x4*>(dst + s4 * 4) = bv;
    }
  }
  __syncthreads();

  // ---- wave-uniform Toeplitz A-fragments: A[m=li][k=quad*8+j] ----
  // conv1: T1[i][j] = h[j - i + 63];  conv2 (negated): -h[64 + i - j].
  bf16x8 A1[5], A2[5];
#pragma unroll
  for (int dd = 0; dd < 5; ++dd) {
    int d = (dd - 2) * 32;   // K-chunk offset j0 - i0
    bf16x8 a1, a2;
#pragma unroll
    for (int j = 0; j < 8; ++j) {
      int k = quad * 8 + j;
      int idx1 = 63 + d + k - li;
      a1[j] = (idx1 >= 0 && idx1 < 128) ? (bf16)hs[idx1] : (bf16)0.f;
      int idx2 = 64 + li - d - k;
      a2[j] = (idx2 >= 0 && idx2 < 128) ? (bf16)(-hs[idx2]) : (bf16)0.f;
    }
    A1[dd] = a1; A2[dd] = a2;
  }

  // ---- conv1: tiles i0 = -64 + 16t, t in [0,41); emit -r to rs ----
  for (int t = wave; t < 41; t += 4) {
    int i0 = -64 + 16 * t;
    f32x4 acc;
    {  // acc init = -y  (C/D: row i = quad*4+e, col b = li)
      bf16x4 yv = *reinterpret_cast<const bf16x4*>(
          ys + li * PY + (i0 + 128) + quad * 4);
      acc[0] = -(float)yv[0]; acc[1] = -(float)yv[1];
      acc[2] = -(float)yv[2]; acc[3] = -(float)yv[3];
    }
#pragma unroll
    for (int dd = 0; dd < 5; ++dd) {
      int d = (dd - 2) * 32;
      bf16x8 bfrag = *reinterpret_cast<const bf16x8*>(
          ys + li * PY + (i0 + d + 128) + quad * 8);
      acc = __builtin_amdgcn_mfma_f32_16x16x32_bf16(A1[dd], bfrag, acc, 0, 0, 0);
    }
    bf16x4 rv;
#pragma unroll
    for (int e = 0; e < 4; ++e) {
      int g = chunk0 + i0 + quad * 4 + e;       // global L position
      float v = (g >= 0 && g < 4096) ? acc[e] : 0.f;  // zero-pad outside row
      rv[e] = (bf16)v;
    }
    *reinterpret_cast<bf16x4*>(rs + li * PR + (i0 + 64) + quad * 4) = rv;
  }
  __syncthreads();

  // ---- conv2 + soft-threshold epilogue: tiles i0 = 16t, t in [0,32) ----
  const float s = step[0];
  for (int t = wave; t < 32; t += 4) {
    int i0 = 16 * t;
    f32x4 acc = {0.f, 0.f, 0.f, 0.f};
#pragma unroll
    for (int dd = 0; dd < 5; ++dd) {
      int d = (dd - 2) * 32;
      bf16x8 bfrag = *reinterpret_cast<const bf16x8*>(
          rs + li * PR + (i0 + d + 64) + quad * 8);
      acc = __builtin_amdgcn_mfma_f32_16x16x32_bf16(A2[dd], bfrag, acc, 0, 0, 0);
    }
    float4 xv;
#pragma unroll
    for (int e = 0; e < 4; ++e) {
      float su = s * acc[e];
      float x = 0.f;
#pragma unroll
      for (int it = 0; it < 5; ++it) {
        x += su;
        float ax = fabsf(x) - LAM;
        ax = ax > 0.f ? ax : 0.f;
        x = copysignf(ax, x);
      }
      (&xv.x)[e] = x;
    }
    *reinterpret_cast<float4*>(
        out + (size_t)(b0 + li) * 4096 + chunk0 + i0 + quad * 4) = xv;
  }
}

extern "C" void kernel_launch(void* const* d_in, const int* in_sizes, int n_in,
                              void* d_out, int out_size, void* d_ws,
                              size_t ws_size, hipStream_t stream) {
  const float* y = (const float*)d_in[0];
  const float* h = (const float*)d_in[1];
  const float* s = (const float*)d_in[2];
  float* out = (float*)d_out;
  ista_mfma<<<dim3(4096 / LC, 256), dim3(256), 0, stream>>>(y, h, s, out);
}